// Round 14
// baseline (121.096 us; speedup 1.0000x reference)
//
#include <hip/hip_runtime.h>

// Problem constants
#define B_    2
#define N_    2048
#define H_    16
#define HD_   64
#define ENC_  512
#define FP_   288
#define CHK_  64
#define NC_   32
#define SSZ_  18720                  // state elems: [65 j][288 f]; SINGLE f16 plane
#define C2C_  0.17677669529663687f   // 1/(4*sqrt(2))
#define EPS_  1e-12f

using s8v   = __attribute__((ext_vector_type(8))) short;     // 8x16-bit carrier
using s4v   = __attribute__((ext_vector_type(4))) short;     // 4x16-bit carrier
using h8v   = __attribute__((ext_vector_type(8))) _Float16;  // 8 f16 (4 VGPRs)
using f4v   = __attribute__((ext_vector_type(4))) float;
using u16x4 = __attribute__((ext_vector_type(4))) unsigned short;
typedef unsigned short ushort_t;

// ---- f16 helpers
__device__ __forceinline__ unsigned short f16q(float x) {
    _Float16 h = (_Float16)x;
    return __builtin_bit_cast(unsigned short, h);
}
__device__ __forceinline__ float f16f(unsigned short u) {
    return (float)__builtin_bit_cast(_Float16, u);
}
__device__ __forceinline__ u16x4 f16q4(float4 v) {
    return (u16x4){f16q(v.x), f16q(v.y), f16q(v.z), f16q(v.w)};
}

#define MFMAH_ __builtin_amdgcn_mfma_f32_16x16x32_f16

// async global->LDS, 16B per lane
__device__ __forceinline__ void gld16(const void* g, void* l) {
    __builtin_amdgcn_global_load_lds(
        (const __attribute__((address_space(1))) unsigned int*)g,
        (__attribute__((address_space(3))) unsigned int*)l, 16, 0, 0);
}

// bijective XCD swizzle (m204)
__device__ __forceinline__ int xcd_swz(int b, int nwg) {
    int q = nwg >> 3, r = nwg & 7;
    int xcd = b & 7, loc = b >> 3;
    return (xcd < r ? xcd * (q + 1) : r * (q + 1) + (xcd - r) * q) + loc;
}

// ---------------------------------------------------------------------------
// split_all: x -> xh ; [Wq;Wk;Wv] -> w1 ; [Wke;Wve] -> w2 ; Wout -> wo.
// ---------------------------------------------------------------------------
#define X_F4   1048576
#define W1_F4  393216
#define W2_F4  327680
#define WO_F4  262144

__global__ __launch_bounds__(256) void split_all(
    const float* __restrict__ x,
    const float* __restrict__ Wq, const float* __restrict__ Wk,
    const float* __restrict__ Wv, const float* __restrict__ Wke,
    const float* __restrict__ Wve, const float* __restrict__ Wout,
    ushort_t* __restrict__ xh,
    ushort_t* __restrict__ w1, ushort_t* __restrict__ w2,
    ushort_t* __restrict__ wo)
{
    int gid = blockIdx.x * 256 + threadIdx.x;
    if (gid < X_F4) {
        ((u16x4*)xh)[gid] = f16q4(((const float4*)x)[gid]);
    } else if (gid < X_F4 + W1_F4) {
        int i = gid - X_F4;
        int row = i >> 8, c4 = i & 255;
        const float* s = (row < 256) ? Wq + (size_t)row * 1024
                       : (row < 512) ? Wk + (size_t)(row - 256) * 1024
                                     : Wv + (size_t)(row - 512) * 1024;
        ((u16x4*)w1)[i] = f16q4(*(const float4*)(s + c4 * 4));
    } else if (gid < X_F4 + W1_F4 + W2_F4) {
        int i = gid - X_F4 - W1_F4;
        int row = i >> 8, c4 = i & 255;
        const float* s = (row < 256) ? Wke + (size_t)row * 1024
                                     : Wve + (size_t)(row - 256) * 1024;
        ((u16x4*)w2)[i] = f16q4(*(const float4*)(s + c4 * 4));
    } else {
        int i = gid - X_F4 - W1_F4 - W2_F4;
        ((u16x4*)wo)[i] = f16q4(((const float4*)Wout)[i]);
    }
}

// ---------------------------------------------------------------------------
// f16 1-pass GEMM body; double-buffered global_load_lds staging.
// ---------------------------------------------------------------------------
template <int SHIFT>
__device__ __forceinline__ void bg128(
    const ushort_t* __restrict__ Ah, const ushort_t* __restrict__ Wh,
    int bx, int by, int rowjump,
    ushort_t* SM, f4v (&acc)[4][4])
{
    int t = threadIdx.x;
    int w = t >> 6, lane = t & 63;
    int row0 = by * 128, col0 = bx * 128;
    int wrow = (w >> 1) * 64, wcol = (w & 1) * 64;
    int fr = lane & 15, g = lane >> 4;

    int c0 = lane, c1 = 64 + lane;
    int r0 = w * 32 + (c0 >> 2), k80 = (c0 & 3) * 8;
    int r1 = w * 32 + (c1 >> 2), k81 = (c1 & 3) * 8;
    int gr0 = row0 + r0, gr1 = row0 + r1;
    size_t a0 = (size_t)(gr0 >> SHIFT) * rowjump + (gr0 & ((1 << SHIFT) - 1));
    size_t a1 = (size_t)(gr1 >> SHIFT) * rowjump + (gr1 & ((1 << SHIFT) - 1));
    const ushort_t* pA0 = Ah + a0 * 1024 + k80;
    const ushort_t* pA1 = Ah + a1 * 1024 + k81;
    const ushort_t* pW0 = Wh + (size_t)(col0 + r0) * 1024 + k80;
    const ushort_t* pW1 = Wh + (size_t)(col0 + r1) * 1024 + k81;
    int woff = w * 1024;

    #pragma unroll
    for (int mt = 0; mt < 4; ++mt)
        #pragma unroll
        for (int nt = 0; nt < 4; ++nt) acc[mt][nt] = (f4v){0.f, 0.f, 0.f, 0.f};

    auto STAGE = [&](int buf, int k0) {
        ushort_t* Bp = SM + buf * 8192;
        gld16(pA0 + k0, Bp + woff);
        gld16(pA1 + k0, Bp + woff + 512);
        gld16(pW0 + k0, Bp + 4096 + woff);
        gld16(pW1 + k0, Bp + 4096 + woff + 512);
    };

    STAGE(0, 0);
    __syncthreads();
    int cur = 0;
    for (int k0 = 0; k0 < 1024; k0 += 32) {
        if (k0 + 32 < 1024) STAGE(cur ^ 1, k0 + 32);
        ushort_t* Bp = SM + cur * 8192;
        h8v a_h[4], b_[4];
        #pragma unroll
        for (int mt = 0; mt < 4; ++mt)
            a_h[mt] = *(const h8v*)&Bp[(wrow + mt * 16 + fr) * 32 + g * 8];
        #pragma unroll
        for (int nt = 0; nt < 4; ++nt)
            b_[nt] = *(const h8v*)&Bp[4096 + (wcol + nt * 16 + fr) * 32 + g * 8];
        #pragma unroll
        for (int mt = 0; mt < 4; ++mt)
            #pragma unroll
            for (int nt = 0; nt < 4; ++nt)
                acc[mt][nt] = MFMAH_(a_h[mt], b_[nt], acc[mt][nt], 0, 0, 0);
        __syncthreads();
        cur ^= 1;
    }
}

// ---------------------------------------------------------------------------
// proj2: main (384 blocks) + enc (80 blocks); all outputs SINGLE f16.
// ---------------------------------------------------------------------------
__global__ __launch_bounds__(256) void proj2(
    const ushort_t* __restrict__ xh,
    const ushort_t* __restrict__ w1, const ushort_t* __restrict__ w2,
    ushort_t* __restrict__ tmpq, ushort_t* __restrict__ tmpk, ushort_t* __restrict__ v,
    ushort_t* __restrict__ tmpke, ushort_t* __restrict__ ve)
{
    __shared__ ushort_t SM[16384];
    f4v acc[4][4];
    int blk = xcd_swz(blockIdx.x, 464);
    int t = threadIdx.x, w = t >> 6, lane = t & 63;
    int wrow = (w >> 1) * 64, wcol = (w & 1) * 64;
    int fr = lane & 15, g = lane >> 4;

    if (blk < 384) {
        int bx = blk % 12, by = blk / 12;
        bg128<12>(xh, w1, bx, by, 0, SM, acc);
        int row0 = by * 128, col0 = bx * 128;
        #pragma unroll
        for (int mt = 0; mt < 4; ++mt)
            #pragma unroll
            for (int nt = 0; nt < 4; ++nt)
                #pragma unroll
                for (int r4 = 0; r4 < 4; ++r4) {
                    int r  = row0 + wrow + mt * 16 + g * 4 + r4;
                    int cc = col0 + wcol + nt * 16 + fr;
                    ushort_t val = f16q(acc[mt][nt][r4]);
                    if (cc < 256)      tmpq[(size_t)r * 256 + cc] = val;
                    else if (cc < 512) tmpk[(size_t)r * 256 + (cc - 256)] = val;
                    else {
                        int c2 = cc - 512, hh = c2 >> 6, jj = c2 & 63;
                        int bb = r >> 11, n = r & 2047;
                        v[(((size_t)(bb * 16 + hh)) * 2048 + n) * 64 + jj] = val;
                    }
                }
    } else {
        int r2 = blk - 384;
        int bx = r2 % 10, by = r2 / 10;
        bg128<9>(xh, w2, bx, by, 2048, SM, acc);
        int row0 = by * 128, col0 = bx * 128;
        #pragma unroll
        for (int mt = 0; mt < 4; ++mt)
            #pragma unroll
            for (int nt = 0; nt < 4; ++nt)
                #pragma unroll
                for (int r4 = 0; r4 < 4; ++r4) {
                    int r  = row0 + wrow + mt * 16 + g * 4 + r4;
                    int cc = col0 + wcol + nt * 16 + fr;
                    ushort_t val = f16q(acc[mt][nt][r4]);
                    if (cc < 256) tmpke[(size_t)r * 256 + cc] = val;
                    else {
                        int c2 = cc - 256, hh = c2 >> 6, jj = c2 & 63;
                        int bb = r >> 9, n = r & 511;
                        ve[(((size_t)(bb * 16 + hh)) * 512 + n) * 64 + jj] = val;
                    }
                }
    }
}

// out_gemm: attn(single f16) @ Wout(f16)^T -> f32 d_out, 1-pass.
__global__ __launch_bounds__(256) void out_gemm(
    const ushort_t* __restrict__ Atn, const ushort_t* __restrict__ Wh,
    float* __restrict__ out)
{
    __shared__ ushort_t SM[16384];
    f4v acc[4][4];
    int blk = xcd_swz(blockIdx.x, 256);
    int bx = blk & 7, by = blk >> 3;
    bg128<12>(Atn, Wh, bx, by, 0, SM, acc);
    int t = threadIdx.x, w = t >> 6, lane = t & 63;
    int wrow = (w >> 1) * 64, wcol = (w & 1) * 64;
    int fr = lane & 15, g = lane >> 4;
    int row0 = by * 128, col0 = bx * 128;
    #pragma unroll
    for (int mt = 0; mt < 4; ++mt)
        #pragma unroll
        for (int nt = 0; nt < 4; ++nt)
            #pragma unroll
            for (int r4 = 0; r4 < 4; ++r4) {
                int r  = row0 + wrow + mt * 16 + g * 4 + r4;
                int cc = col0 + wcol + nt * 16 + fr;
                out[(size_t)r * 1024 + cc] = acc[mt][nt][r4];
            }
}

// ---------------------------------------------------------------------------
// FUSED state+prefix kernel.  Block = (bh, fgroup); wave owns one f-tile of
// 16.  run = acc[5] persists in registers: accumulate encoder (8 m-units),
// then per chunk c: STORE run as prefix[bh][c], then accumulate chunk c.
// k/v for unit u+1 register-prefetched while computing unit u.
// Grid = 32 bh * 5 fgroups = 160 blocks.
// ---------------------------------------------------------------------------
__global__ __launch_bounds__(256) void state_prefix(
    const ushort_t* __restrict__ kpe, const ushort_t* __restrict__ ve,
    const ushort_t* __restrict__ kpc, const ushort_t* __restrict__ vc,
    ushort_t* __restrict__ Spre)
{
    __shared__ float ksT[17 * 68];
    __shared__ ushort_t VTH[80 * 72];
    int blk = blockIdx.x;
    int fg = blk % 5, bh = blk / 5;
    int b = bh >> 4, h = bh & 15;
    int t = threadIdx.x;
    int w = t >> 6, lane = t & 63, fr = lane & 15, g = lane >> 4;
    int ft = fg * 4 + w;            // wave's f-tile (18 total; fg=4 -> waves 2,3 idle in MFMA)
    bool fvalid = ft < 18;

    // feature decomposition for this lane's f column (constant over the loop)
    int f = ft * 16 + fr;
    int fi, fj; float scale;
    if (f == 0)       { fi = 16; fj = 16; scale = 1.0f; }
    else if (f < 17)  { fi = f - 1; fj = 16; scale = 0.5f; }
    else if (f < 273) { fi = (f - 17) >> 4; fj = (f - 17) & 15; scale = C2C_; }
    else              { fi = 16; fj = 16; scale = 0.0f; }

    // zero the A-pad rows (65..79) once; never overwritten
    for (int i = t; i < 15 * 72; i += 256) VTH[65 * 72 + i] = 0;

    int rk_r = t >> 2, rk_q4 = t & 3;       // k staging coords
    int mv = t & 63, jg = t >> 6, j0 = jg * 16;  // v staging coords

    auto ld_unit = [&](int u, s4v& rk, s8v& rv0, s8v& rv1) {
        if (u < 8) {
            rk = *(const s4v*)&kpe[((size_t)b * 512 + u * 64 + rk_r) * 256 + h * 16 + rk_q4 * 4];
            const ushort_t* vr = &ve[((size_t)bh * 512 + u * 64 + mv) * HD_ + j0];
            rv0 = *(const s8v*)vr; rv1 = *(const s8v*)(vr + 8);
        } else {
            int c = u - 8;
            rk = *(const s4v*)&kpc[((size_t)b * 2048 + c * 64 + rk_r) * 256 + h * 16 + rk_q4 * 4];
            const ushort_t* vr = &vc[((size_t)bh * 2048 + c * 64 + mv) * HD_ + j0];
            rv0 = *(const s8v*)vr; rv1 = *(const s8v*)(vr + 8);
        }
    };
    auto wr_unit = [&](const s4v& rk, const s8v& rv0, const s8v& rv1) {
        ksT[(rk_q4 * 4 + 0) * 68 + rk_r] = f16f((ushort_t)rk[0]);
        ksT[(rk_q4 * 4 + 1) * 68 + rk_r] = f16f((ushort_t)rk[1]);
        ksT[(rk_q4 * 4 + 2) * 68 + rk_r] = f16f((ushort_t)rk[2]);
        ksT[(rk_q4 * 4 + 3) * 68 + rk_r] = f16f((ushort_t)rk[3]);
        if (t < 64) ksT[16 * 68 + t] = 1.0f;
        #pragma unroll
        for (int e = 0; e < 8; ++e) VTH[(j0 + e) * 72 + mv] = (ushort_t)rv0[e];
        #pragma unroll
        for (int e = 0; e < 8; ++e) VTH[(j0 + 8 + e) * 72 + mv] = (ushort_t)rv1[e];
        if (t < 64) VTH[64 * 72 + t] = 0x3C00;   // ones row (denominator)
    };

    f4v run[5];
    #pragma unroll
    for (int jt = 0; jt < 5; ++jt) run[jt] = (f4v){0.f, 0.f, 0.f, 0.f};

    s4v rk; s8v rv0, rv1;
    ld_unit(0, rk, rv0, rv1);
    wr_unit(rk, rv0, rv1);
    __syncthreads();

    for (int u = 0; u < 40; ++u) {
        s4v nk; s8v nv0, nv1;
        if (u < 39) ld_unit(u + 1, nk, nv0, nv1);

        // store prefix BEFORE accumulating this chunk (exclusive prefix)
        if (u >= 8 && fvalid) {
            ushort_t* Sg = Spre + ((size_t)bh * NC_ + (u - 8)) * SSZ_;
            #pragma unroll
            for (int jt = 0; jt < 5; ++jt)
                #pragma unroll
                for (int r4 = 0; r4 < 4; ++r4) {
                    int j = jt * 16 + g * 4 + r4;
                    if (j < 65) Sg[(size_t)j * FP_ + f] = f16q(run[jt][r4]);
                }
        }

        // MFMA: run += Vext^T @ feat  (feature fragment generated per lane)
        if (fvalid) {
            #pragma unroll
            for (int ks2 = 0; ks2 < 2; ++ks2) {
                const float* pa = ksT + fi * 68 + ks2 * 32 + g * 8;
                const float* pb = ksT + fj * 68 + ks2 * 32 + g * 8;
                h8v bv;
                #pragma unroll
                for (int e = 0; e < 8; ++e) bv[e] = (_Float16)(pa[e] * pb[e] * scale);
                #pragma unroll
                for (int jt = 0; jt < 5; ++jt) {
                    h8v av = *(const h8v*)&VTH[(jt * 16 + fr) * 72 + ks2 * 32 + g * 8];
                    run[jt] = MFMAH_(av, bv, run[jt], 0, 0, 0);
                }
            }
        }
        __syncthreads();                 // done reading LDS for unit u
        if (u < 39) {
            wr_unit(nk, nv0, nv1);
            __syncthreads();             // LDS ready for unit u+1
        }
    }
}

// ---------------------------------------------------------------------------
// attn_chunk: all-f16 inputs.  QK^T 1-pass; Y1 = A @ V; Y2 = QF @ S with
// register-prefetched state slices.
// ---------------------------------------------------------------------------
template<int FW>
__device__ __forceinline__ void y2_issue(
    const ushort_t* __restrict__ Sth, int f0, int t, s8v& r0, s8v& r1, s8v& r2)
{
    constexpr int NS = FW / 8;
    constexpr int TOT = 65 * NS;
    int s1 = t + 256, s2 = t + 512;
    r0 = *(const s8v*)(Sth + (size_t)(t / NS) * FP_ + f0 + (t % NS) * 8);
    if (s1 < TOT) r1 = *(const s8v*)(Sth + (size_t)(s1 / NS) * FP_ + f0 + (s1 % NS) * 8);
    if (FW == 64 && s2 < TOT) r2 = *(const s8v*)(Sth + (size_t)(s2 / NS) * FP_ + f0 + (s2 % NS) * 8);
}

template<int FW>
__device__ __forceinline__ void y2_write(
    ushort_t* STH, int t, const s8v& r0, const s8v& r1, const s8v& r2)
{
    constexpr int NS = FW / 8;
    constexpr int TOT = 65 * NS;
    int s1 = t + 256, s2 = t + 512;
    *(s8v*)&STH[(t / NS) * 72 + (t % NS) * 8] = r0;
    if (s1 < TOT) *(s8v*)&STH[(s1 / NS) * 72 + (s1 % NS) * 8] = r1;
    if (FW == 64 && s2 < TOT) *(s8v*)&STH[(s2 / NS) * 72 + (s2 % NS) * 8] = r2;
}

template<int FW>
__device__ __forceinline__ void qf_gen(int f0, const float* qs, ushort_t* QF1, int t)
{
    for (int i = t; i < 64 * FW; i += 256) {
        int row = i / FW, cc = i % FW;
        int f = f0 + cc;
        float qv;
        if (f == 0)       qv = 1.0f;
        else if (f < 17)  qv = qs[row * 20 + (f - 1)] * 0.5f;
        else if (f < 273) qv = qs[row * 20 + ((f - 17) >> 4)] * qs[row * 20 + ((f - 17) & 15)] * C2C_;
        else              qv = 0.0f;
        QF1[row * 72 + cc] = f16q(qv);
    }
}

template<int FW>
__device__ __forceinline__ void y2_mfma(
    const ushort_t* QF1, const ushort_t* STH,
    f4v (&acc)[5], int w, int fr, int g)
{
    #pragma unroll
    for (int ks2 = 0; ks2 < FW / 32; ++ks2) {
        h8v a = *(const h8v*)&QF1[(16 * w + fr) * 72 + ks2 * 32 + g * 8];
        #pragma unroll
        for (int jt = 0; jt < 5; ++jt) {
            h8v b = *(const h8v*)&STH[(jt * 16 + fr) * 72 + ks2 * 32 + g * 8];
            acc[jt] = MFMAH_(a, b, acc[jt], 0, 0, 0);
        }
    }
}

__global__ __launch_bounds__(256) void attn_chunk(
    const ushort_t* __restrict__ qp, const ushort_t* __restrict__ kp,
    const ushort_t* __restrict__ v, const ushort_t* __restrict__ Spre,
    ushort_t* __restrict__ atn)
{
    __shared__ ushort_t U[14976];
    __shared__ float qs[64 * 20];
    __shared__ float den_s[64];
    ushort_t* AH  = U;            // [64][72]  f16 (A)
    ushort_t* QH  = U + 9216;     // [64][40]
    ushort_t* KH  = U + 11776;    // [64][40]  -> ends 14336
    ushort_t* VTH = U + 9216;     // [80][72]  (after QK^T)
    ushort_t* QF1 = U;            // [64][72]  (Y2; overlays AH after Y1)
    ushort_t* STH = U + 9216;     // [80][72]  (Y2; rows 65-79 stay 0)

    int bid = blockIdx.x;
    int bh = bid >> 5, c = bid & 31;
    int b = bh >> 4, h = bh & 15;
    int t = threadIdx.x;
    int w = t >> 6, lane = t & 63, fr = lane & 15, g = lane >> 4;
    int rowbase = b * N_ + c * CHK_;
    const ushort_t* Sth = Spre + ((size_t)bh * NC_ + c) * SSZ_;

    // ---- issue q/k loads (f16)
    int rqk = t >> 2, q4 = t & 3;
    s4v qv = *(const s4v*)&qp[(size_t)(rowbase + rqk) * 256 + h * 16 + q4 * 4];
    s4v kv = *(const s4v*)&kp[(size_t)(rowbase + rqk) * 256 + h * 16 + q4 * 4];
    // ---- prefetch: state slice 0 + V tile (fly under QK^T)
    s8v rA0 = {}, rA1 = {}, rA2 = {};
    y2_issue<64>(Sth, 0, t, rA0, rA1, rA2);
    int mv = t & 63, jg0 = t >> 6;
    const ushort_t* vr = &v[((size_t)bh * N_ + c * CHK_ + mv) * HD_ + jg0 * 16];
    s8v rv0 = *(const s8v*)(vr);
    s8v rv1 = *(const s8v*)(vr + 8);

    // ---- stage q/k (f16 copies) + qs f32
    {
        *(s4v*)&QH[rqk * 40 + q4 * 4] = qv;
        *(s4v*)&KH[rqk * 40 + q4 * 4] = kv;
        s4v z4 = (s4v){0, 0, 0, 0};
        *(s4v*)&QH[rqk * 40 + 16 + q4 * 4] = z4;
        *(s4v*)&KH[rqk * 40 + 16 + q4 * 4] = z4;
        qs[rqk * 20 + q4 * 4 + 0] = f16f((ushort_t)qv[0]);
        qs[rqk * 20 + q4 * 4 + 1] = f16f((ushort_t)qv[1]);
        qs[rqk * 20 + q4 * 4 + 2] = f16f((ushort_t)qv[2]);
        qs[rqk * 20 + q4 * 4 + 3] = f16f((ushort_t)qv[3]);
    }
    __syncthreads();

    // ---- phase A: QK^T (f16 1-pass), poly+tril, store f16 AH
    {
        h8v qh = *(const h8v*)&QH[(16 * w + fr) * 40 + g * 8];
        f4v sacc[4];
        #pragma unroll
        for (int jt = 0; jt < 4; ++jt) sacc[jt] = (f4v){0.f, 0.f, 0.f, 0.f};
        #pragma unroll
        for (int jt = 0; jt < 4; ++jt) {
            h8v kh = *(const h8v*)&KH[(jt * 16 + fr) * 40 + g * 8];
            sacc[jt] = MFMAH_(qh, kh, sacc[jt], 0, 0, 0);
        }
        __syncthreads();   // QH/KH dead after this barrier (sacc in regs)
        #pragma unroll
        for (int jt = 0; jt < 4; ++jt)
            #pragma unroll
            for (int r4 = 0; r4 < 4; ++r4) {
                int row = 16 * w + g * 4 + r4, col = jt * 16 + fr;
                float s = sacc[jt][r4];
                float a = (row >= col) ? (fmaf(s, 0.25f, 1.0f) + s * s * 0.03125f) : 0.f;
                AH[row * 72 + col] = f16q(a);
            }
    }
    // ---- write V tile from prefetched regs + ones/zero rows
    {
        int j0 = jg0 * 16;
        #pragma unroll
        for (int e = 0; e < 8; ++e) VTH[(j0 + e) * 72 + mv] = (ushort_t)rv0[e];
        #pragma unroll
        for (int e = 0; e < 8; ++e) VTH[(j0 + 8 + e) * 72 + mv] = (ushort_t)rv1[e];
    }
    if (t < 64) VTH[64 * 72 + t] = 0x3C00;          // f16 1.0 (denominator row)
    for (int i = t; i < 15 * 72; i += 256) VTH[65 * 72 + i] = 0;
    __syncthreads();

    // ---- Y1: acc += A @ VT
    f4v acc[5];
    #pragma unroll
    for (int jt = 0; jt < 5; ++jt) acc[jt] = (f4v){0.f, 0.f, 0.f, 0.f};
    #pragma unroll
    for (int ks2 = 0; ks2 < 2; ++ks2) {
        h8v ah = *(const h8v*)&AH[(16 * w + fr) * 72 + ks2 * 32 + g * 8];
        #pragma unroll
        for (int jt = 0; jt < 5; ++jt) {
            h8v b = *(const h8v*)&VTH[(jt * 16 + fr) * 72 + ks2 * 32 + g * 8];
            acc[jt] = MFMAH_(ah, b, acc[jt], 0, 0, 0);
        }
    }
    __syncthreads();

    // ---- Y2: 5 state slices, register-prefetched (slice 0 already in rA*)
    #pragma unroll
    for (int p = 0; p < 4; ++p) {
        y2_write<64>(STH, t, rA0, rA1, rA2);
        if (p < 3) y2_issue<64>(Sth, (p + 1) * 64, t, rA0, rA1, rA2);
        else       y2_issue<32>(Sth, 256,          t, rA0, rA1, rA2);
        qf_gen<64>(p * 64, qs, QF1, t);
        __syncthreads();
        y2_mfma<64>(QF1, STH, acc, w, fr, g);
        __syncthreads();
    }
    y2_write<32>(STH, t, rA0, rA1, rA2);
    qf_gen<32>(256, qs, QF1, t);
    __syncthreads();
    y2_mfma<32>(QF1, STH, acc, w, fr, g);

    // ---- epilogue: divide by denominator, store single f16
    if (fr == 0) {
        #pragma unroll
        for (int r4 = 0; r4 < 4; ++r4)
            den_s[16 * w + g * 4 + r4] = acc[4][r4];
    }
    __syncthreads();
    #pragma unroll
    for (int r4 = 0; r4 < 4; ++r4) {
        float z = 1.0f / (den_s[16 * w + g * 4 + r4] + EPS_);
        int row = rowbase + 16 * w + g * 4 + r4;
        #pragma unroll
        for (int jt = 0; jt < 4; ++jt) {
            float val = acc[jt][r4] * z;
            atn[(size_t)row * 1024 + h * 64 + jt * 16 + fr] = f16q(val);
        }
    }
}

// ---------------------------------------------------------------------------
extern "C" void kernel_launch(void* const* d_in, const int* in_sizes, int n_in,
                              void* d_out, int out_size, void* d_ws, size_t ws_size,
                              hipStream_t stream)
{
    const float* x    = (const float*)d_in[0];
    const float* Wq   = (const float*)d_in[1];
    const float* Wk   = (const float*)d_in[2];
    const float* Wv   = (const float*)d_in[3];
    const float* Wke  = (const float*)d_in[4];
    const float* Wve  = (const float*)d_in[5];
    const float* Wout = (const float*)d_in[6];
    float* out = (float*)d_out;

    // all-f16 workspace (~64 MB)
    ushort_t* usws  = (ushort_t*)d_ws;
    ushort_t* tmpq  = usws;                            // 1,048,576
    ushort_t* tmpk  = tmpq  + (size_t)1048576;         // 1,048,576
    ushort_t* tmpke = tmpk  + (size_t)1048576;         //   262,144
    ushort_t* v     = tmpke + (size_t)262144;          // 4,194,304
    ushort_t* ve    = v     + (size_t)4194304;         // 1,048,576
    ushort_t* Sloc  = ve    + (size_t)1048576;         // 19,169,280 (prefix states)
    ushort_t* xh    = Sloc  + (size_t)19169280;        // 4,194,304
    ushort_t* wo    = xh    + (size_t)4194304;         // 1,048,576
    // overlays:
    ushort_t* w1 = Sloc;                               // dead before state_prefix
    ushort_t* w2 = w1 + (size_t)1572864;
    ushort_t* atn = xh;                                // xh dead after proj2

    dim3 blk(256);

    split_all<<<7936, blk, 0, stream>>>(x, Wq, Wk, Wv, Wke, Wve, Wout,
                                        xh, w1, w2, wo);
    proj2<<<464, blk, 0, stream>>>(xh, w1, w2, tmpq, tmpk, v, tmpke, ve);
    state_prefix<<<160, blk, 0, stream>>>(tmpke, ve, tmpk, v, Sloc);
    attn_chunk<<<32 * NC_, blk, 0, stream>>>(tmpq, tmpk, v, Sloc, atn);
    out_gemm<<<256, blk, 0, stream>>>(atn, wo, out);
}

// Round 15
// 103.142 us; speedup vs baseline: 1.1741x; 1.1741x over previous
//
#include <hip/hip_runtime.h>

// Problem constants
#define B_    2
#define N_    2048
#define H_    16
#define HD_   64
#define ENC_  512
#define FP_   288
#define CHK_  64
#define NC_   32
#define SSZ_  18720                  // state elems: [65 j][288 f]; SINGLE f16 plane
#define C2C_  0.17677669529663687f   // 1/(4*sqrt(2))
#define EPS_  1e-12f

using s8v   = __attribute__((ext_vector_type(8))) short;     // 8x16-bit carrier
using s4v   = __attribute__((ext_vector_type(4))) short;     // 4x16-bit carrier
using h8v   = __attribute__((ext_vector_type(8))) _Float16;  // 8 f16 (4 VGPRs)
using f4v   = __attribute__((ext_vector_type(4))) float;
using u16x4 = __attribute__((ext_vector_type(4))) unsigned short;
typedef unsigned short ushort_t;

// ---- f16 helpers
__device__ __forceinline__ unsigned short f16q(float x) {
    _Float16 h = (_Float16)x;
    return __builtin_bit_cast(unsigned short, h);
}
__device__ __forceinline__ float f16f(unsigned short u) {
    return (float)__builtin_bit_cast(_Float16, u);
}
__device__ __forceinline__ u16x4 f16q4(float4 v) {
    return (u16x4){f16q(v.x), f16q(v.y), f16q(v.z), f16q(v.w)};
}

#define MFMAH_ __builtin_amdgcn_mfma_f32_16x16x32_f16

// async global->LDS, 16B per lane
__device__ __forceinline__ void gld16(const void* g, void* l) {
    __builtin_amdgcn_global_load_lds(
        (const __attribute__((address_space(1))) unsigned int*)g,
        (__attribute__((address_space(3))) unsigned int*)l, 16, 0, 0);
}

// bijective XCD swizzle (m204)
__device__ __forceinline__ int xcd_swz(int b, int nwg) {
    int q = nwg >> 3, r = nwg & 7;
    int xcd = b & 7, loc = b >> 3;
    return (xcd < r ? xcd * (q + 1) : r * (q + 1) + (xcd - r) * q) + loc;
}

// ---------------------------------------------------------------------------
// split_all: x -> xh ; [Wq;Wk;Wv] -> w1 ; [Wke;Wve] -> w2 ; Wout -> wo.
// ---------------------------------------------------------------------------
#define X_F4   1048576
#define W1_F4  393216
#define W2_F4  327680
#define WO_F4  262144

__global__ __launch_bounds__(256) void split_all(
    const float* __restrict__ x,
    const float* __restrict__ Wq, const float* __restrict__ Wk,
    const float* __restrict__ Wv, const float* __restrict__ Wke,
    const float* __restrict__ Wve, const float* __restrict__ Wout,
    ushort_t* __restrict__ xh,
    ushort_t* __restrict__ w1, ushort_t* __restrict__ w2,
    ushort_t* __restrict__ wo)
{
    int gid = blockIdx.x * 256 + threadIdx.x;
    if (gid < X_F4) {
        ((u16x4*)xh)[gid] = f16q4(((const float4*)x)[gid]);
    } else if (gid < X_F4 + W1_F4) {
        int i = gid - X_F4;
        int row = i >> 8, c4 = i & 255;
        const float* s = (row < 256) ? Wq + (size_t)row * 1024
                       : (row < 512) ? Wk + (size_t)(row - 256) * 1024
                                     : Wv + (size_t)(row - 512) * 1024;
        ((u16x4*)w1)[i] = f16q4(*(const float4*)(s + c4 * 4));
    } else if (gid < X_F4 + W1_F4 + W2_F4) {
        int i = gid - X_F4 - W1_F4;
        int row = i >> 8, c4 = i & 255;
        const float* s = (row < 256) ? Wke + (size_t)row * 1024
                                     : Wve + (size_t)(row - 256) * 1024;
        ((u16x4*)w2)[i] = f16q4(*(const float4*)(s + c4 * 4));
    } else {
        int i = gid - X_F4 - W1_F4 - W2_F4;
        ((u16x4*)wo)[i] = f16q4(((const float4*)Wout)[i]);
    }
}

// ---------------------------------------------------------------------------
// f16 1-pass GEMM body; double-buffered global_load_lds staging.
// ---------------------------------------------------------------------------
template <int SHIFT>
__device__ __forceinline__ void bg128(
    const ushort_t* __restrict__ Ah, const ushort_t* __restrict__ Wh,
    int bx, int by, int rowjump,
    ushort_t* SM, f4v (&acc)[4][4])
{
    int t = threadIdx.x;
    int w = t >> 6, lane = t & 63;
    int row0 = by * 128, col0 = bx * 128;
    int wrow = (w >> 1) * 64, wcol = (w & 1) * 64;
    int fr = lane & 15, g = lane >> 4;

    int c0 = lane, c1 = 64 + lane;
    int r0 = w * 32 + (c0 >> 2), k80 = (c0 & 3) * 8;
    int r1 = w * 32 + (c1 >> 2), k81 = (c1 & 3) * 8;
    int gr0 = row0 + r0, gr1 = row0 + r1;
    size_t a0 = (size_t)(gr0 >> SHIFT) * rowjump + (gr0 & ((1 << SHIFT) - 1));
    size_t a1 = (size_t)(gr1 >> SHIFT) * rowjump + (gr1 & ((1 << SHIFT) - 1));
    const ushort_t* pA0 = Ah + a0 * 1024 + k80;
    const ushort_t* pA1 = Ah + a1 * 1024 + k81;
    const ushort_t* pW0 = Wh + (size_t)(col0 + r0) * 1024 + k80;
    const ushort_t* pW1 = Wh + (size_t)(col0 + r1) * 1024 + k81;
    int woff = w * 1024;

    #pragma unroll
    for (int mt = 0; mt < 4; ++mt)
        #pragma unroll
        for (int nt = 0; nt < 4; ++nt) acc[mt][nt] = (f4v){0.f, 0.f, 0.f, 0.f};

    auto STAGE = [&](int buf, int k0) {
        ushort_t* Bp = SM + buf * 8192;
        gld16(pA0 + k0, Bp + woff);
        gld16(pA1 + k0, Bp + woff + 512);
        gld16(pW0 + k0, Bp + 4096 + woff);
        gld16(pW1 + k0, Bp + 4096 + woff + 512);
    };

    STAGE(0, 0);
    __syncthreads();
    int cur = 0;
    for (int k0 = 0; k0 < 1024; k0 += 32) {
        if (k0 + 32 < 1024) STAGE(cur ^ 1, k0 + 32);
        ushort_t* Bp = SM + cur * 8192;
        h8v a_h[4], b_[4];
        #pragma unroll
        for (int mt = 0; mt < 4; ++mt)
            a_h[mt] = *(const h8v*)&Bp[(wrow + mt * 16 + fr) * 32 + g * 8];
        #pragma unroll
        for (int nt = 0; nt < 4; ++nt)
            b_[nt] = *(const h8v*)&Bp[4096 + (wcol + nt * 16 + fr) * 32 + g * 8];
        #pragma unroll
        for (int mt = 0; mt < 4; ++mt)
            #pragma unroll
            for (int nt = 0; nt < 4; ++nt)
                acc[mt][nt] = MFMAH_(a_h[mt], b_[nt], acc[mt][nt], 0, 0, 0);
        __syncthreads();
        cur ^= 1;
    }
}

// ---------------------------------------------------------------------------
// proj2: main (384 blocks) + enc (80 blocks); all outputs SINGLE f16.
// ---------------------------------------------------------------------------
__global__ __launch_bounds__(256) void proj2(
    const ushort_t* __restrict__ xh,
    const ushort_t* __restrict__ w1, const ushort_t* __restrict__ w2,
    ushort_t* __restrict__ tmpq, ushort_t* __restrict__ tmpk, ushort_t* __restrict__ v,
    ushort_t* __restrict__ tmpke, ushort_t* __restrict__ ve)
{
    __shared__ ushort_t SM[16384];
    f4v acc[4][4];
    int blk = xcd_swz(blockIdx.x, 464);
    int t = threadIdx.x, w = t >> 6, lane = t & 63;
    int wrow = (w >> 1) * 64, wcol = (w & 1) * 64;
    int fr = lane & 15, g = lane >> 4;

    if (blk < 384) {
        int bx = blk % 12, by = blk / 12;
        bg128<12>(xh, w1, bx, by, 0, SM, acc);
        int row0 = by * 128, col0 = bx * 128;
        #pragma unroll
        for (int mt = 0; mt < 4; ++mt)
            #pragma unroll
            for (int nt = 0; nt < 4; ++nt)
                #pragma unroll
                for (int r4 = 0; r4 < 4; ++r4) {
                    int r  = row0 + wrow + mt * 16 + g * 4 + r4;
                    int cc = col0 + wcol + nt * 16 + fr;
                    ushort_t val = f16q(acc[mt][nt][r4]);
                    if (cc < 256)      tmpq[(size_t)r * 256 + cc] = val;
                    else if (cc < 512) tmpk[(size_t)r * 256 + (cc - 256)] = val;
                    else {
                        int c2 = cc - 512, hh = c2 >> 6, jj = c2 & 63;
                        int bb = r >> 11, n = r & 2047;
                        v[(((size_t)(bb * 16 + hh)) * 2048 + n) * 64 + jj] = val;
                    }
                }
    } else {
        int r2 = blk - 384;
        int bx = r2 % 10, by = r2 / 10;
        bg128<9>(xh, w2, bx, by, 2048, SM, acc);
        int row0 = by * 128, col0 = bx * 128;
        #pragma unroll
        for (int mt = 0; mt < 4; ++mt)
            #pragma unroll
            for (int nt = 0; nt < 4; ++nt)
                #pragma unroll
                for (int r4 = 0; r4 < 4; ++r4) {
                    int r  = row0 + wrow + mt * 16 + g * 4 + r4;
                    int cc = col0 + wcol + nt * 16 + fr;
                    ushort_t val = f16q(acc[mt][nt][r4]);
                    if (cc < 256) tmpke[(size_t)r * 256 + cc] = val;
                    else {
                        int c2 = cc - 256, hh = c2 >> 6, jj = c2 & 63;
                        int bb = r >> 9, n = r & 511;
                        ve[(((size_t)(bb * 16 + hh)) * 512 + n) * 64 + jj] = val;
                    }
                }
    }
}

// out_gemm: attn(single f16) @ Wout(f16)^T -> f32 d_out, 1-pass.
__global__ __launch_bounds__(256) void out_gemm(
    const ushort_t* __restrict__ Atn, const ushort_t* __restrict__ Wh,
    float* __restrict__ out)
{
    __shared__ ushort_t SM[16384];
    f4v acc[4][4];
    int blk = xcd_swz(blockIdx.x, 256);
    int bx = blk & 7, by = blk >> 3;
    bg128<12>(Atn, Wh, bx, by, 0, SM, acc);
    int t = threadIdx.x, w = t >> 6, lane = t & 63;
    int wrow = (w >> 1) * 64, wcol = (w & 1) * 64;
    int fr = lane & 15, g = lane >> 4;
    int row0 = by * 128, col0 = bx * 128;
    #pragma unroll
    for (int mt = 0; mt < 4; ++mt)
        #pragma unroll
        for (int nt = 0; nt < 4; ++nt)
            #pragma unroll
            for (int r4 = 0; r4 < 4; ++r4) {
                int r  = row0 + wrow + mt * 16 + g * 4 + r4;
                int cc = col0 + wcol + nt * 16 + fr;
                out[(size_t)r * 1024 + cc] = acc[mt][nt][r4];
            }
}

// ---------------------------------------------------------------------------
// MFMA state kernel, 1-pass, f16 inputs: A = Vext f16, B = on-the-fly features.
// ---------------------------------------------------------------------------
__device__ __forceinline__ void st_stage(
    const ushort_t* __restrict__ Kp, const ushort_t* __restrict__ V,
    size_t krow0, size_t vrow0, int h, int t,
    float* ksT, ushort_t* VTH)
{
    {
        int r = t >> 2, q4 = t & 3;
        s4v kv = *(const s4v*)&Kp[(krow0 + r) * 256 + h * 16 + q4 * 4];
        ksT[(q4 * 4 + 0) * 68 + r] = f16f((ushort_t)kv[0]);
        ksT[(q4 * 4 + 1) * 68 + r] = f16f((ushort_t)kv[1]);
        ksT[(q4 * 4 + 2) * 68 + r] = f16f((ushort_t)kv[2]);
        ksT[(q4 * 4 + 3) * 68 + r] = f16f((ushort_t)kv[3]);
    }
    if (t < 64) ksT[16 * 68 + t] = 1.0f;
    {
        int r = t & 63, jg = t >> 6;
        const ushort_t* vrow = &V[(vrow0 + r) * HD_ + jg * 16];
        s8v v0 = *(const s8v*)(vrow);
        s8v v1 = *(const s8v*)(vrow + 8);
        int j0 = jg * 16;
        #pragma unroll
        for (int e = 0; e < 8; ++e) VTH[(j0 + e) * 72 + r] = (ushort_t)v0[e];
        #pragma unroll
        for (int e = 0; e < 8; ++e) VTH[(j0 + 8 + e) * 72 + r] = (ushort_t)v1[e];
    }
    if (t < 64) VTH[64 * 72 + t] = 0x3C00;  // f16 1.0
}

__device__ __forceinline__ void st_ftile(
    const float* ksT, int ft, int fr, int g,
    const h8v (&AHf)[2][5], f4v (&acc)[5])
{
    int f = ft * 16 + fr;
    int fi, fj; float scale;
    if (f == 0)       { fi = 16; fj = 16; scale = 1.0f; }
    else if (f < 17)  { fi = f - 1; fj = 16; scale = 0.5f; }
    else if (f < 273) { fi = (f - 17) >> 4; fj = (f - 17) & 15; scale = C2C_; }
    else              { fi = 16; fj = 16; scale = 0.0f; }
    #pragma unroll
    for (int ks2 = 0; ks2 < 2; ++ks2) {
        const float* pa = ksT + fi * 68 + ks2 * 32 + g * 8;
        const float* pb = ksT + fj * 68 + ks2 * 32 + g * 8;
        h8v bv;
        #pragma unroll
        for (int e = 0; e < 8; ++e) bv[e] = (_Float16)(pa[e] * pb[e] * scale);
        #pragma unroll
        for (int jt = 0; jt < 5; ++jt)
            acc[jt] = MFMAH_(AHf[ks2][jt], bv, acc[jt], 0, 0, 0);
    }
}

__global__ __launch_bounds__(256) void state_all(
    const ushort_t* __restrict__ Kpe, const ushort_t* __restrict__ Ve, ushort_t* __restrict__ Se,
    const ushort_t* __restrict__ Kpc, const ushort_t* __restrict__ Vc, ushort_t* __restrict__ Sc)
{
    __shared__ float ksT[17 * 68];
    __shared__ ushort_t VTH[80 * 72];
    int blk = blockIdx.x, t = threadIdx.x;
    int w = t >> 6, lane = t & 63, fr = lane & 15, g = lane >> 4;

    for (int i = t; i < 15 * 72; i += 256) VTH[65 * 72 + i] = 0;

    if (blk >= 160) {
        int b2 = blk - 160;
        int c = b2 & 31, bh = b2 >> 5;
        int b = bh >> 4, h = bh & 15;
        ushort_t* Sg = Sc + ((size_t)bh * NC_ + c) * SSZ_;
        st_stage(Kpc, Vc, (size_t)b * 2048 + c * 64, (size_t)bh * 2048 + c * 64,
                 h, t, ksT, VTH);
        __syncthreads();
        h8v AHf[2][5];
        #pragma unroll
        for (int ks2 = 0; ks2 < 2; ++ks2)
            #pragma unroll
            for (int jt = 0; jt < 5; ++jt)
                AHf[ks2][jt] = *(const h8v*)&VTH[(jt * 16 + fr) * 72 + ks2 * 32 + g * 8];
        for (int ft = w; ft < 18; ft += 4) {
            f4v acc[5];
            #pragma unroll
            for (int jt = 0; jt < 5; ++jt) acc[jt] = (f4v){0.f, 0.f, 0.f, 0.f};
            st_ftile(ksT, ft, fr, g, AHf, acc);
            #pragma unroll
            for (int jt = 0; jt < 5; ++jt)
                #pragma unroll
                for (int r4 = 0; r4 < 4; ++r4) {
                    int j = jt * 16 + g * 4 + r4;
                    if (j < 65) Sg[(size_t)j * FP_ + ft * 16 + fr] = f16q(acc[jt][r4]);
                }
        }
    } else {
        int bh = blk / 5, fg = blk % 5;
        int b = bh >> 4, h = bh & 15;
        int ft = fg * 4 + w;
        ushort_t* Sg = Se + (size_t)bh * SSZ_;
        f4v acc[5];
        #pragma unroll
        for (int jt = 0; jt < 5; ++jt) acc[jt] = (f4v){0.f, 0.f, 0.f, 0.f};
        for (int m0 = 0; m0 < 512; m0 += 64) {
            if (m0) __syncthreads();
            st_stage(Kpe, Ve, (size_t)b * 512 + m0, (size_t)bh * 512 + m0,
                     h, t, ksT, VTH);
            __syncthreads();
            if (ft < 18) {
                h8v AHf[2][5];
                #pragma unroll
                for (int ks2 = 0; ks2 < 2; ++ks2)
                    #pragma unroll
                    for (int jt = 0; jt < 5; ++jt)
                        AHf[ks2][jt] = *(const h8v*)&VTH[(jt * 16 + fr) * 72 + ks2 * 32 + g * 8];
                st_ftile(ksT, ft, fr, g, AHf, acc);
            }
        }
        if (ft < 18) {
            #pragma unroll
            for (int jt = 0; jt < 5; ++jt)
                #pragma unroll
                for (int r4 = 0; r4 < 4; ++r4) {
                    int j = jt * 16 + g * 4 + r4;
                    if (j < 65) Sg[(size_t)j * FP_ + ft * 16 + fr] = f16q(acc[jt][r4]);
                }
        }
    }
}

// ---------------------------------------------------------------------------
// Exclusive prefix over single-f16 states, in place.  All 32 chunk loads
// issued up front (static unroll -> registers), then running-sum stores.
// ---------------------------------------------------------------------------
__global__ __launch_bounds__(256) void prefix_scan(
    ushort_t* __restrict__ Sloc, const ushort_t* __restrict__ Senc)
{
    const int Q = SSZ_ / 4;    // 4680 quad(4-short) groups
    int gid = blockIdx.x * 256 + threadIdx.x;
    if (gid >= 32 * Q) return;
    int bh = gid / Q, e = gid - bh * Q;
    s4v ev = *(const s4v*)(Senc + (size_t)bh * SSZ_ + e * 4);
    float run[4];
    #pragma unroll
    for (int u = 0; u < 4; ++u) run[u] = f16f((ushort_t)ev[u]);
    ushort_t* Sb = Sloc + (size_t)bh * NC_ * SSZ_ + e * 4;
    s4v tv[NC_];
    #pragma unroll
    for (int c2 = 0; c2 < NC_; ++c2)
        tv[c2] = *(const s4v*)(Sb + (size_t)c2 * SSZ_);
    #pragma unroll
    for (int c2 = 0; c2 < NC_; ++c2) {
        s4v o;
        #pragma unroll
        for (int u = 0; u < 4; ++u) {
            o[u] = (short)f16q(run[u]);
            run[u] += f16f((ushort_t)tv[c2][u]);
        }
        *(s4v*)(Sb + (size_t)c2 * SSZ_) = o;
    }
}

// ---------------------------------------------------------------------------
// attn_chunk: all-f16 inputs.  QK^T 1-pass; Y1 = A @ V; Y2 = QF @ S with
// register-prefetched state slices.
// ---------------------------------------------------------------------------
template<int FW>
__device__ __forceinline__ void y2_issue(
    const ushort_t* __restrict__ Sth, int f0, int t, s8v& r0, s8v& r1, s8v& r2)
{
    constexpr int NS = FW / 8;
    constexpr int TOT = 65 * NS;
    int s1 = t + 256, s2 = t + 512;
    r0 = *(const s8v*)(Sth + (size_t)(t / NS) * FP_ + f0 + (t % NS) * 8);
    if (s1 < TOT) r1 = *(const s8v*)(Sth + (size_t)(s1 / NS) * FP_ + f0 + (s1 % NS) * 8);
    if (FW == 64 && s2 < TOT) r2 = *(const s8v*)(Sth + (size_t)(s2 / NS) * FP_ + f0 + (s2 % NS) * 8);
}

template<int FW>
__device__ __forceinline__ void y2_write(
    ushort_t* STH, int t, const s8v& r0, const s8v& r1, const s8v& r2)
{
    constexpr int NS = FW / 8;
    constexpr int TOT = 65 * NS;
    int s1 = t + 256, s2 = t + 512;
    *(s8v*)&STH[(t / NS) * 72 + (t % NS) * 8] = r0;
    if (s1 < TOT) *(s8v*)&STH[(s1 / NS) * 72 + (s1 % NS) * 8] = r1;
    if (FW == 64 && s2 < TOT) *(s8v*)&STH[(s2 / NS) * 72 + (s2 % NS) * 8] = r2;
}

template<int FW>
__device__ __forceinline__ void qf_gen(int f0, const float* qs, ushort_t* QF1, int t)
{
    for (int i = t; i < 64 * FW; i += 256) {
        int row = i / FW, cc = i % FW;
        int f = f0 + cc;
        float qv;
        if (f == 0)       qv = 1.0f;
        else if (f < 17)  qv = qs[row * 20 + (f - 1)] * 0.5f;
        else if (f < 273) qv = qs[row * 20 + ((f - 17) >> 4)] * qs[row * 20 + ((f - 17) & 15)] * C2C_;
        else              qv = 0.0f;
        QF1[row * 72 + cc] = f16q(qv);
    }
}

template<int FW>
__device__ __forceinline__ void y2_mfma(
    const ushort_t* QF1, const ushort_t* STH,
    f4v (&acc)[5], int w, int fr, int g)
{
    #pragma unroll
    for (int ks2 = 0; ks2 < FW / 32; ++ks2) {
        h8v a = *(const h8v*)&QF1[(16 * w + fr) * 72 + ks2 * 32 + g * 8];
        #pragma unroll
        for (int jt = 0; jt < 5; ++jt) {
            h8v b = *(const h8v*)&STH[(jt * 16 + fr) * 72 + ks2 * 32 + g * 8];
            acc[jt] = MFMAH_(a, b, acc[jt], 0, 0, 0);
        }
    }
}

__global__ __launch_bounds__(256) void attn_chunk(
    const ushort_t* __restrict__ qp, const ushort_t* __restrict__ kp,
    const ushort_t* __restrict__ v, const ushort_t* __restrict__ Spre,
    ushort_t* __restrict__ atn)
{
    __shared__ ushort_t U[14976];
    __shared__ float qs[64 * 20];
    __shared__ float den_s[64];
    ushort_t* AH  = U;            // [64][72]  f16 (A)
    ushort_t* QH  = U + 9216;     // [64][40]
    ushort_t* KH  = U + 11776;    // [64][40]  -> ends 14336
    ushort_t* VTH = U + 9216;     // [80][72]  (after QK^T)
    ushort_t* QF1 = U;            // [64][72]  (Y2; overlays AH after Y1)
    ushort_t* STH = U + 9216;     // [80][72]  (Y2; rows 65-79 stay 0)

    int bid = blockIdx.x;
    int bh = bid >> 5, c = bid & 31;
    int b = bh >> 4, h = bh & 15;
    int t = threadIdx.x;
    int w = t >> 6, lane = t & 63, fr = lane & 15, g = lane >> 4;
    int rowbase = b * N_ + c * CHK_;
    const ushort_t* Sth = Spre + ((size_t)bh * NC_ + c) * SSZ_;

    // ---- issue q/k loads (f16)
    int rqk = t >> 2, q4 = t & 3;
    s4v qv = *(const s4v*)&qp[(size_t)(rowbase + rqk) * 256 + h * 16 + q4 * 4];
    s4v kv = *(const s4v*)&kp[(size_t)(rowbase + rqk) * 256 + h * 16 + q4 * 4];
    // ---- prefetch: state slice 0 + V tile (fly under QK^T)
    s8v rA0 = {}, rA1 = {}, rA2 = {};
    y2_issue<64>(Sth, 0, t, rA0, rA1, rA2);
    int mv = t & 63, jg0 = t >> 6;
    const ushort_t* vr = &v[((size_t)bh * N_ + c * CHK_ + mv) * HD_ + jg0 * 16];
    s8v rv0 = *(const s8v*)(vr);
    s8v rv1 = *(const s8v*)(vr + 8);

    // ---- stage q/k (f16 copies) + qs f32
    {
        *(s4v*)&QH[rqk * 40 + q4 * 4] = qv;
        *(s4v*)&KH[rqk * 40 + q4 * 4] = kv;
        s4v z4 = (s4v){0, 0, 0, 0};
        *(s4v*)&QH[rqk * 40 + 16 + q4 * 4] = z4;
        *(s4v*)&KH[rqk * 40 + 16 + q4 * 4] = z4;
        qs[rqk * 20 + q4 * 4 + 0] = f16f((ushort_t)qv[0]);
        qs[rqk * 20 + q4 * 4 + 1] = f16f((ushort_t)qv[1]);
        qs[rqk * 20 + q4 * 4 + 2] = f16f((ushort_t)qv[2]);
        qs[rqk * 20 + q4 * 4 + 3] = f16f((ushort_t)qv[3]);
    }
    __syncthreads();

    // ---- phase A: QK^T (f16 1-pass), poly+tril, store f16 AH
    {
        h8v qh = *(const h8v*)&QH[(16 * w + fr) * 40 + g * 8];
        f4v sacc[4];
        #pragma unroll
        for (int jt = 0; jt < 4; ++jt) sacc[jt] = (f4v){0.f, 0.f, 0.f, 0.f};
        #pragma unroll
        for (int jt = 0; jt < 4; ++jt) {
            h8v kh = *(const h8v*)&KH[(jt * 16 + fr) * 40 + g * 8];
            sacc[jt] = MFMAH_(qh, kh, sacc[jt], 0, 0, 0);
        }
        __syncthreads();   // QH/KH dead after this barrier (sacc in regs)
        #pragma unroll
        for (int jt = 0; jt < 4; ++jt)
            #pragma unroll
            for (int r4 = 0; r4 < 4; ++r4) {
                int row = 16 * w + g * 4 + r4, col = jt * 16 + fr;
                float s = sacc[jt][r4];
                float a = (row >= col) ? (fmaf(s, 0.25f, 1.0f) + s * s * 0.03125f) : 0.f;
                AH[row * 72 + col] = f16q(a);
            }
    }
    // ---- write V tile from prefetched regs + ones/zero rows
    {
        int j0 = jg0 * 16;
        #pragma unroll
        for (int e = 0; e < 8; ++e) VTH[(j0 + e) * 72 + mv] = (ushort_t)rv0[e];
        #pragma unroll
        for (int e = 0; e < 8; ++e) VTH[(j0 + 8 + e) * 72 + mv] = (ushort_t)rv1[e];
    }
    if (t < 64) VTH[64 * 72 + t] = 0x3C00;          // f16 1.0 (denominator row)
    for (int i = t; i < 15 * 72; i += 256) VTH[65 * 72 + i] = 0;
    __syncthreads();

    // ---- Y1: acc += A @ VT
    f4v acc[5];
    #pragma unroll
    for (int jt = 0; jt < 5; ++jt) acc[jt] = (f4v){0.f, 0.f, 0.f, 0.f};
    #pragma unroll
    for (int ks2 = 0; ks2 < 2; ++ks2) {
        h8v ah = *(const h8v*)&AH[(16 * w + fr) * 72 + ks2 * 32 + g * 8];
        #pragma unroll
        for (int jt = 0; jt < 5; ++jt) {
            h8v b = *(const h8v*)&VTH[(jt * 16 + fr) * 72 + ks2 * 32 + g * 8];
            acc[jt] = MFMAH_(ah, b, acc[jt], 0, 0, 0);
        }
    }
    __syncthreads();

    // ---- Y2: 5 state slices, register-prefetched (slice 0 already in rA*)
    #pragma unroll
    for (int p = 0; p < 4; ++p) {
        y2_write<64>(STH, t, rA0, rA1, rA2);
        if (p < 3) y2_issue<64>(Sth, (p + 1) * 64, t, rA0, rA1, rA2);
        else       y2_issue<32>(Sth, 256,          t, rA0, rA1, rA2);
        qf_gen<64>(p * 64, qs, QF1, t);
        __syncthreads();
        y2_mfma<64>(QF1, STH, acc, w, fr, g);
        __syncthreads();
    }
    y2_write<32>(STH, t, rA0, rA1, rA2);
    qf_gen<32>(256, qs, QF1, t);
    __syncthreads();
    y2_mfma<32>(QF1, STH, acc, w, fr, g);

    // ---- epilogue: divide by denominator, store single f16
    if (fr == 0) {
        #pragma unroll
        for (int r4 = 0; r4 < 4; ++r4)
            den_s[16 * w + g * 4 + r4] = acc[4][r4];
    }
    __syncthreads();
    #pragma unroll
    for (int r4 = 0; r4 < 4; ++r4) {
        float z = 1.0f / (den_s[16 * w + g * 4 + r4] + EPS_);
        int row = rowbase + 16 * w + g * 4 + r4;
        #pragma unroll
        for (int jt = 0; jt < 4; ++jt) {
            float val = acc[jt][r4] * z;
            atn[(size_t)row * 1024 + h * 64 + jt * 16 + fr] = f16q(val);
        }
    }
}

// ---------------------------------------------------------------------------
extern "C" void kernel_launch(void* const* d_in, const int* in_sizes, int n_in,
                              void* d_out, int out_size, void* d_ws, size_t ws_size,
                              hipStream_t stream)
{
    const float* x    = (const float*)d_in[0];
    const float* Wq   = (const float*)d_in[1];
    const float* Wk   = (const float*)d_in[2];
    const float* Wv   = (const float*)d_in[3];
    const float* Wke  = (const float*)d_in[4];
    const float* Wve  = (const float*)d_in[5];
    const float* Wout = (const float*)d_in[6];
    float* out = (float*)d_out;

    // all-f16 workspace (~65 MB)
    ushort_t* usws  = (ushort_t*)d_ws;
    ushort_t* tmpq  = usws;                            // 1,048,576
    ushort_t* tmpk  = tmpq  + (size_t)1048576;         // 1,048,576
    ushort_t* tmpke = tmpk  + (size_t)1048576;         //   262,144
    ushort_t* v     = tmpke + (size_t)262144;          // 4,194,304
    ushort_t* ve    = v     + (size_t)4194304;         // 1,048,576
    ushort_t* Sloc  = ve    + (size_t)1048576;         // 19,169,280
    ushort_t* Senc  = Sloc  + (size_t)19169280;        //   599,040
    ushort_t* xh    = Senc  + (size_t)599040;          // 4,194,304
    ushort_t* wo    = xh    + (size_t)4194304;         // 1,048,576
    // overlays:
    ushort_t* w1 = Sloc;                               // dead before state_all
    ushort_t* w2 = w1 + (size_t)1572864;
    ushort_t* atn = xh;                                // xh dead after proj2

    dim3 blk(256);

    split_all<<<7936, blk, 0, stream>>>(x, Wq, Wk, Wv, Wke, Wve, Wout,
                                        xh, w1, w2, wo);
    proj2<<<464, blk, 0, stream>>>(xh, w1, w2, tmpq, tmpk, v, tmpke, ve);
    state_all<<<160 + 32 * NC_, blk, 0, stream>>>(tmpke, ve, Senc, tmpk, v, Sloc);
    prefix_scan<<<585, blk, 0, stream>>>(Sloc, Senc);
    attn_chunk<<<32 * NC_, blk, 0, stream>>>(tmpq, tmpk, v, Sloc, atn);
    out_gemm<<<256, blk, 0, stream>>>(atn, wo, out);
}